// Round 1
// baseline (6242.291 us; speedup 1.0000x reference)
//
#include <hip/hip_runtime.h>

#define N_USERS 100000
#define N_ITEMS 200000
#define N_NODES 300000
#define EMB 64
#define NNZ_C 9600000

// ---- elementwise: ego = acc = concat(user, item), float4-vectorized ----
__global__ void init_kernel(const float4* __restrict__ ue, const float4* __restrict__ ie,
                            float4* __restrict__ ego, float4* __restrict__ acc) {
    const int user4 = N_USERS * EMB / 4;   // 1.6M
    const int total4 = N_NODES * EMB / 4;  // 4.8M
    int stride = gridDim.x * blockDim.x;
    for (int i = blockIdx.x * blockDim.x + threadIdx.x; i < total4; i += stride) {
        float4 v = (i < user4) ? ue[i] : ie[i - user4];
        ego[i] = v;
        acc[i] = v;
    }
}

__global__ void zero_kernel(float4* __restrict__ p, int n4) {
    int stride = gridDim.x * blockDim.x;
    float4 z = make_float4(0.f, 0.f, 0.f, 0.f);
    for (int i = blockIdx.x * blockDim.x + threadIdx.x; i < n4; i += stride) p[i] = z;
}

// ---- COO SpMM: one wave (64 lanes) per edge, lane = embedding dim ----
__global__ void spmm_kernel(const int* __restrict__ rows, const int* __restrict__ cols,
                            const float* __restrict__ vals,
                            const float* __restrict__ ego_in, float* __restrict__ ego_out) {
    int wave = (blockIdx.x * blockDim.x + threadIdx.x) >> 6;
    int lane = threadIdx.x & 63;
    int nwaves = (gridDim.x * blockDim.x) >> 6;
    for (int e = wave; e < NNZ_C; e += nwaves) {
        int r = rows[e];
        int c = cols[e];
        float v = vals[e];
        float x = ego_in[c * EMB + lane];          // coalesced 256B gather
        atomicAdd(&ego_out[r * EMB + lane], v * x); // coalesced 256B scatter-add
    }
}

// ---- acc = (acc + ego) * scale ----
__global__ void add_kernel(float4* __restrict__ acc, const float4* __restrict__ ego,
                           float scale, int n4) {
    int stride = gridDim.x * blockDim.x;
    for (int i = blockIdx.x * blockDim.x + threadIdx.x; i < n4; i += stride) {
        float4 a = acc[i];
        float4 g = ego[i];
        a.x = (a.x + g.x) * scale;
        a.y = (a.y + g.y) * scale;
        a.z = (a.z + g.z) * scale;
        a.w = (a.w + g.w) * scale;
        acc[i] = a;
    }
}

extern "C" void kernel_launch(void* const* d_in, const int* in_sizes, int n_in,
                              void* d_out, int out_size, void* d_ws, size_t ws_size,
                              hipStream_t stream) {
    const float* user_emb = (const float*)d_in[0];
    const float* item_emb = (const float*)d_in[1];
    const int*   adj_rows = (const int*)d_in[2];
    const int*   adj_cols = (const int*)d_in[3];
    const float* adj_vals = (const float*)d_in[4];
    float* acc = (float*)d_out;                       // [N_NODES * EMB]

    float* ego_a = (float*)d_ws;                      // 76.8 MB
    float* ego_b = ego_a + (size_t)N_NODES * EMB;     // 76.8 MB

    const int total4 = N_NODES * EMB / 4;
    const int EW_BLOCKS = 4096, EW_THREADS = 256;
    const int SP_BLOCKS = 4096, SP_THREADS = 256;     // 16384 waves, ~586 edges/wave

    // acc = ego0 = concat(user, item)
    init_kernel<<<EW_BLOCKS, EW_THREADS, 0, stream>>>(
        (const float4*)user_emb, (const float4*)item_emb,
        (float4*)ego_a, (float4*)acc);

    float* ego_in = ego_a;
    float* ego_out = ego_b;
    for (int layer = 0; layer < 3; ++layer) {
        zero_kernel<<<EW_BLOCKS, EW_THREADS, 0, stream>>>((float4*)ego_out, total4);
        spmm_kernel<<<SP_BLOCKS, SP_THREADS, 0, stream>>>(
            adj_rows, adj_cols, adj_vals, ego_in, ego_out);
        float scale = (layer == 2) ? 0.25f : 1.0f;    // fuse final /4 into last add
        add_kernel<<<EW_BLOCKS, EW_THREADS, 0, stream>>>(
            (float4*)acc, (const float4*)ego_out, scale, total4);
        // ping-pong
        float* t = ego_in; ego_in = ego_out; ego_out = t;
    }
}

// Round 2
// 2162.141 us; speedup vs baseline: 2.8871x; 2.8871x over previous
//
#include <hip/hip_runtime.h>

#define N_USERS 100000
#define N_ITEMS 200000
#define N_NODES 300000
#define EMB 64
#define NNZ_C 9600000
#define SCAN_BLK 1024
#define N_SCAN_BLOCKS ((N_NODES + SCAN_BLK - 1) / SCAN_BLK)   // 293

// ==================== elementwise ====================

__global__ void init_kernel(const float4* __restrict__ ue, const float4* __restrict__ ie,
                            float4* __restrict__ ego, float4* __restrict__ acc) {
    const int user4 = N_USERS * EMB / 4;
    const int total4 = N_NODES * EMB / 4;
    int stride = gridDim.x * blockDim.x;
    for (int i = blockIdx.x * blockDim.x + threadIdx.x; i < total4; i += stride) {
        float4 v = (i < user4) ? ue[i] : ie[i - user4];
        ego[i] = v;
        acc[i] = v;
    }
}

__global__ void zero_int_kernel(int* __restrict__ p, int n) {
    int stride = gridDim.x * blockDim.x;
    for (int i = blockIdx.x * blockDim.x + threadIdx.x; i < n; i += stride) p[i] = 0;
}

// ==================== counting sort by row ====================

__global__ void hist_kernel(const int* __restrict__ rows, int* __restrict__ counts) {
    int stride = gridDim.x * blockDim.x;
    for (int e = blockIdx.x * blockDim.x + threadIdx.x; e < NNZ_C; e += stride)
        atomicAdd(&counts[rows[e]], 1);
}

// per-block exclusive scan of counts chunk -> row_ptr (partial), block total -> blockSums
__global__ void scan_a_kernel(const int* __restrict__ counts, int* __restrict__ row_ptr,
                              int* __restrict__ blockSums) {
    __shared__ int s[SCAN_BLK];
    int tid = threadIdx.x;
    int base = blockIdx.x * SCAN_BLK;
    int idx = base + tid;
    int x = (idx < N_NODES) ? counts[idx] : 0;
    s[tid] = x;
    __syncthreads();
    for (int off = 1; off < SCAN_BLK; off <<= 1) {
        int t = (tid >= off) ? s[tid - off] : 0;
        __syncthreads();
        s[tid] += t;
        __syncthreads();
    }
    if (idx < N_NODES) row_ptr[idx] = s[tid] - x;      // exclusive partial
    if (tid == SCAN_BLK - 1) blockSums[blockIdx.x] = s[tid];
}

// exclusive scan of blockSums (293 entries) in one block
__global__ void scan_b_kernel(int* __restrict__ blockSums) {
    __shared__ int s[512];
    int tid = threadIdx.x;
    int x = (tid < N_SCAN_BLOCKS) ? blockSums[tid] : 0;
    s[tid] = x;
    __syncthreads();
    for (int off = 1; off < 512; off <<= 1) {
        int t = (tid >= off) ? s[tid - off] : 0;
        __syncthreads();
        s[tid] += t;
        __syncthreads();
    }
    if (tid < N_SCAN_BLOCKS) blockSums[tid] = s[tid] - x;  // exclusive
}

// add block offset -> final row_ptr; also fill mutable offsets copy for scatter
__global__ void scan_c_kernel(int* __restrict__ row_ptr, const int* __restrict__ blockSums,
                              int* __restrict__ offsets) {
    int tid = threadIdx.x;
    int idx = blockIdx.x * SCAN_BLK + tid;
    if (idx < N_NODES) {
        int v = row_ptr[idx] + blockSums[blockIdx.x];
        row_ptr[idx] = v;
        offsets[idx] = v;
    }
    if (blockIdx.x == 0 && tid == 0) row_ptr[N_NODES] = NNZ_C;
}

__global__ void scatter_kernel(const int* __restrict__ rows, const int* __restrict__ cols,
                               const float* __restrict__ vals, int* __restrict__ offsets,
                               uint2* __restrict__ cv) {
    int stride = gridDim.x * blockDim.x;
    for (int e = blockIdx.x * blockDim.x + threadIdx.x; e < NNZ_C; e += stride) {
        int r = rows[e];
        int pos = atomicAdd(&offsets[r], 1);
        cv[pos] = make_uint2((unsigned)cols[e], __float_as_uint(vals[e]));
    }
}

// ==================== segmented SpMM, no atomics ====================
// one quarter-wave (16 lanes x float4 = 64 floats) per row; fused acc update
__global__ void spmm_seg_kernel(const int* __restrict__ row_ptr, const uint2* __restrict__ cv,
                                const float4* __restrict__ ego_in, float4* __restrict__ ego_out,
                                float4* __restrict__ acc, float scale, int write_ego) {
    int sub = (blockIdx.x * blockDim.x + threadIdx.x) >> 4;
    int lane = threadIdx.x & 15;
    int nsub = (gridDim.x * blockDim.x) >> 4;
    for (int r = sub; r < N_NODES; r += nsub) {
        int beg = row_ptr[r], end = row_ptr[r + 1];
        float4 s0 = make_float4(0.f, 0.f, 0.f, 0.f);
        float4 s1 = make_float4(0.f, 0.f, 0.f, 0.f);
        int e = beg;
        for (; e + 2 <= end; e += 2) {                 // unroll-2, independent gathers
            uint2 p0 = cv[e];
            uint2 p1 = cv[e + 1];
            float4 x0 = ego_in[p0.x * 16 + lane];
            float4 x1 = ego_in[p1.x * 16 + lane];
            float v0 = __uint_as_float(p0.y);
            float v1 = __uint_as_float(p1.y);
            s0.x += v0 * x0.x; s0.y += v0 * x0.y; s0.z += v0 * x0.z; s0.w += v0 * x0.w;
            s1.x += v1 * x1.x; s1.y += v1 * x1.y; s1.z += v1 * x1.z; s1.w += v1 * x1.w;
        }
        if (e < end) {
            uint2 p0 = cv[e];
            float4 x0 = ego_in[p0.x * 16 + lane];
            float v0 = __uint_as_float(p0.y);
            s0.x += v0 * x0.x; s0.y += v0 * x0.y; s0.z += v0 * x0.z; s0.w += v0 * x0.w;
        }
        float4 s = make_float4(s0.x + s1.x, s0.y + s1.y, s0.z + s1.z, s0.w + s1.w);
        int o = r * 16 + lane;
        float4 a = acc[o];
        a.x = (a.x + s.x) * scale;
        a.y = (a.y + s.y) * scale;
        a.z = (a.z + s.z) * scale;
        a.w = (a.w + s.w) * scale;
        acc[o] = a;
        if (write_ego) ego_out[o] = s;
    }
}

// ==================== fallback (round-1 atomic path) ====================

__global__ void zero4_kernel(float4* __restrict__ p, int n4) {
    int stride = gridDim.x * blockDim.x;
    float4 z = make_float4(0.f, 0.f, 0.f, 0.f);
    for (int i = blockIdx.x * blockDim.x + threadIdx.x; i < n4; i += stride) p[i] = z;
}

__global__ void spmm_atomic_kernel(const int* __restrict__ rows, const int* __restrict__ cols,
                                   const float* __restrict__ vals,
                                   const float* __restrict__ ego_in, float* __restrict__ ego_out) {
    int wave = (blockIdx.x * blockDim.x + threadIdx.x) >> 6;
    int lane = threadIdx.x & 63;
    int nwaves = (gridDim.x * blockDim.x) >> 6;
    for (int e = wave; e < NNZ_C; e += nwaves) {
        int r = rows[e];
        int c = cols[e];
        float v = vals[e];
        float x = ego_in[c * EMB + lane];
        atomicAdd(&ego_out[r * EMB + lane], v * x);
    }
}

__global__ void add_kernel(float4* __restrict__ acc, const float4* __restrict__ ego,
                           float scale, int n4) {
    int stride = gridDim.x * blockDim.x;
    for (int i = blockIdx.x * blockDim.x + threadIdx.x; i < n4; i += stride) {
        float4 a = acc[i];
        float4 g = ego[i];
        a.x = (a.x + g.x) * scale;
        a.y = (a.y + g.y) * scale;
        a.z = (a.z + g.z) * scale;
        a.w = (a.w + g.w) * scale;
        acc[i] = a;
    }
}

// ==================== launch ====================

extern "C" void kernel_launch(void* const* d_in, const int* in_sizes, int n_in,
                              void* d_out, int out_size, void* d_ws, size_t ws_size,
                              hipStream_t stream) {
    const float* user_emb = (const float*)d_in[0];
    const float* item_emb = (const float*)d_in[1];
    const int*   adj_rows = (const int*)d_in[2];
    const int*   adj_cols = (const int*)d_in[3];
    const float* adj_vals = (const float*)d_in[4];
    float* acc = (float*)d_out;

    const size_t egoN = (size_t)N_NODES * EMB;               // 19.2M floats
    float* ego_a = (float*)d_ws;
    float* ego_b = ego_a + egoN;

    const int total4 = N_NODES * EMB / 4;
    const int EW_BLOCKS = 4096, EW_THREADS = 256;

    // sorted-path workspace layout (after the two ego buffers)
    uint2* cv       = (uint2*)(ego_b + egoN);                 // 76.8 MB
    int*   row_ptr  = (int*)(cv + (size_t)NNZ_C);             // (N+1)*4
    int*   offsets  = row_ptr + (N_NODES + 1);                // N*4
    int*   counts   = offsets + N_NODES;                      // N*4
    int*   blockSums = counts + N_NODES;                      // 293*4
    size_t needed = (size_t)((char*)(blockSums + 512) - (char*)d_ws);

    if (ws_size >= needed) {
        // ---- build CSR (counting sort by row) ----
        zero_int_kernel<<<1024, 256, 0, stream>>>(counts, N_NODES);
        hist_kernel<<<2048, 256, 0, stream>>>(adj_rows, counts);
        scan_a_kernel<<<N_SCAN_BLOCKS, SCAN_BLK, 0, stream>>>(counts, row_ptr, blockSums);
        scan_b_kernel<<<1, 512, 0, stream>>>(blockSums);
        scan_c_kernel<<<N_SCAN_BLOCKS, SCAN_BLK, 0, stream>>>(row_ptr, blockSums, offsets);
        scatter_kernel<<<2048, 256, 0, stream>>>(adj_rows, adj_cols, adj_vals, offsets, cv);

        // ---- propagate ----
        init_kernel<<<EW_BLOCKS, EW_THREADS, 0, stream>>>(
            (const float4*)user_emb, (const float4*)item_emb,
            (float4*)ego_a, (float4*)acc);

        // layer 1: a -> b ; layer 2: b -> a ; layer 3: a -> (discard), scale 0.25
        spmm_seg_kernel<<<2048, 256, 0, stream>>>(row_ptr, cv, (const float4*)ego_a,
                                                  (float4*)ego_b, (float4*)acc, 1.0f, 1);
        spmm_seg_kernel<<<2048, 256, 0, stream>>>(row_ptr, cv, (const float4*)ego_b,
                                                  (float4*)ego_a, (float4*)acc, 1.0f, 1);
        spmm_seg_kernel<<<2048, 256, 0, stream>>>(row_ptr, cv, (const float4*)ego_a,
                                                  (float4*)ego_b, (float4*)acc, 0.25f, 0);
    } else {
        // ---- fallback: atomic COO path (round-1) ----
        init_kernel<<<EW_BLOCKS, EW_THREADS, 0, stream>>>(
            (const float4*)user_emb, (const float4*)item_emb,
            (float4*)ego_a, (float4*)acc);
        float* ego_in = ego_a;
        float* ego_out = ego_b;
        for (int layer = 0; layer < 3; ++layer) {
            zero4_kernel<<<EW_BLOCKS, EW_THREADS, 0, stream>>>((float4*)ego_out, total4);
            spmm_atomic_kernel<<<4096, 256, 0, stream>>>(
                adj_rows, adj_cols, adj_vals, ego_in, ego_out);
            float scale = (layer == 2) ? 0.25f : 1.0f;
            add_kernel<<<EW_BLOCKS, EW_THREADS, 0, stream>>>(
                (float4*)acc, (const float4*)ego_out, scale, total4);
            float* t = ego_in; ego_in = ego_out; ego_out = t;
        }
    }
}